// Round 7
// baseline (446.135 us; speedup 1.0000x reference)
//
#include <hip/hip_runtime.h>

// LinearMPC PGD, round 7: round-5 tiering + XOR swizzle + single-barrier dbuf.
// 128 blocks x 512 thr (8 waves, 2/SIMD, 256 regs/wave = max-capacity config;
// reg file is 512 regs/SIMD so this is the proven sweet spot).
// Wave w owns cols [w*64,+64) = 4 MFMA n-tiles:
//   T0,T1: bf16 B-frags in registers (128 regs)
//   T2:    H rows in LDS (128 rows, XOR-swizzled -> conflict-free b128)
//   T3:    ks 0..7 in registers (32 regs), ks 8..15 streamed from L2 (64 KB/CU/iter)
// u: fp32 master in regs; bf16 copy double-buffered in LDS (2x16 KB) -> ONE barrier/iter.
// LDS = 128 KB (H) + 32 KB (u dbuf) = 160 KiB exactly.
// Lessons: R2 no cross-block comm; R3 spill sentinel = WRITE_SIZE; R5 LDS-pipe-bound;
// R6 NEVER use inline-asm MFMA (unprotected SW-managed hazards -> garbage).

typedef unsigned short u16t;
typedef __attribute__((ext_vector_type(8))) short short8;
typedef __attribute__((ext_vector_type(4))) float floatx4;

#define DYN_LDS 163840   // 128*512*2 + 2*16*512*2

__device__ __forceinline__ u16t f32_to_bf16(float x) {
    unsigned int u = __builtin_bit_cast(unsigned int, x);
    u = (u + 0x7FFFu + ((u >> 16) & 1u)) >> 16;   // RNE
    return (u16t)u;
}

__global__ void convert_H_bf16(const float* __restrict__ H, u16t* __restrict__ Hb) {
    int idx = blockIdx.x * 256 + threadIdx.x;   // 1024 x 256 = 262144
    Hb[idx] = f32_to_bf16(H[idx]);
}

#define MFMA(a, b, c) __builtin_amdgcn_mfma_f32_16x16x32_bf16((a), (b), (c), 0, 0, 0)

__global__ __launch_bounds__(512, 2)
void pgd_kernel7(const float* __restrict__ xref,   // [2048][65][8]
                 const u16t*  __restrict__ Hb,     // [512][512] bf16
                 const float* __restrict__ Phi,    // [65][8][8]
                 const float* __restrict__ Q,      // [8][8]
                 float* __restrict__ out)          // [2048][512]
{
    extern __shared__ __align__(16) char smem[];
    u16t* Hl  = (u16t*)smem;                    // [128 rows][512] swizzled, 131072 B
    u16t* ub0 = (u16t*)(smem + 131072);         // [16][512] swizzled, 16384 B
    u16t* ub1 = (u16t*)(smem + 131072 + 16384); // [16][512]

    const int tid  = threadIdx.x;
    const int lane = tid & 63;
    const int w    = tid >> 6;        // wave 0..7
    const int quad = lane >> 4;       // 0..3
    const int lcol = lane & 15;       // 0..15
    const int l7   = lcol & 7;
    const int b0   = blockIdx.x * 16;
    const int colbase = w * 64;

    // ---- stage T2 H-rows into LDS, XOR-swizzled chunks of 8 shorts ----
    // LDS row r (0..127) holds H row (r>>4)*64 + 32 + (r&15); chunk c at c^(r&7)
    for (int e = tid; e < 8192; e += 512) {
        int r = e >> 6, c = e & 63;
        int hrow = (r >> 4) * 64 + 32 + (r & 15);
        *(short8*)&Hl[r * 512 + ((c ^ (r & 7)) * 8)] =
            *(const short8*)&Hb[(long)hrow * 512 + c * 8];
    }
    // ---- zero u buffer 0 (u0 = 0) ----
    for (int e = tid; e < 4096; e += 512) ((unsigned*)ub0)[e] = 0u;

    // ---- register B-fragments: T0,T1 full (128 regs), T3 ks 0..7 (32 regs) ----
    short8 hfragA[2][16];
    #pragma unroll
    for (int t = 0; t < 2; ++t) {
        const u16t* hrow = Hb + (long)(colbase + t * 16 + lcol) * 512;
        #pragma unroll
        for (int ks = 0; ks < 16; ++ks)
            hfragA[t][ks] = *(const short8*)&hrow[ks * 32 + quad * 8];
    }
    short8 frag3[8];
    {
        const u16t* hrow = Hb + (long)(colbase + 48 + lcol) * 512;
        #pragma unroll
        for (int ks = 0; ks < 8; ++ks)
            frag3[ks] = *(const short8*)&hrow[ks * 32 + quad * 8];
    }

    // ---- f (linear term) + u master, per-thread regs, C/D layout ----
    float f_reg[4][4], u_reg[4][4];
    #pragma unroll
    for (int T = 0; T < 4; ++T) {
        int c = colbase + T * 16 + lcol;
        int k = c >> 3, i = c & 7;
        #pragma unroll
        for (int r = 0; r < 4; ++r) {
            int m = quad * 4 + r;
            const float* xr = xref + (long)(b0 + m) * 520;
            float s = 0.f;
            #pragma unroll
            for (int j = 0; j < 8; ++j) {
                float z = 0.f;
                #pragma unroll
                for (int l = 0; l < 8; ++l) z += Q[j * 8 + l] * (xr[k * 8 + l] - xr[l]);
                s += Phi[k * 64 + i * 8 + j] * z;
            }
            f_reg[T][r] = -2.0f * s;
            u_reg[T][r] = 0.0f;
        }
    }
    __syncthreads();

    // LDS b-read base for T2 (LDS row = w*16 + lcol, swizzle key l7)
    const u16t* h2 = Hl + (w * 16 + lcol) * 512;
    // streamed half of T3: ks 8..15 of H row colbase+48+lcol; rolling +2 prefetch
    const u16t* hb3 = Hb + (long)(colbase + 48 + lcol) * 512;
    short8 sb0 = *(const short8*)&hb3[8 * 32 + quad * 8];
    short8 sb1 = *(const short8*)&hb3[9 * 32 + quad * 8];

    u16t* rb = ub0;   // read buffer (current u)
    u16t* wb = ub1;   // write buffer (next u)

    for (int it = 0; it < 100; ++it) {
        floatx4 acc[4];
        #pragma unroll
        for (int T = 0; T < 4; ++T) acc[T] = (floatx4){0.f, 0.f, 0.f, 0.f};

        // ---- ks 0..7: all-register T3 ----
        #pragma unroll
        for (int ks = 0; ks < 8; ++ks) {
            const int sc = ((ks * 4 + quad) ^ l7) * 8;   // swizzled chunk offset (shorts)
            short8 a  = *(const short8*)&rb[lcol * 512 + sc];
            short8 b2 = *(const short8*)&h2[sc];
            acc[0] = MFMA(a, hfragA[0][ks], acc[0]);
            acc[1] = MFMA(a, hfragA[1][ks], acc[1]);
            acc[2] = MFMA(a, b2, acc[2]);
            acc[3] = MFMA(a, frag3[ks], acc[3]);
        }
        // ---- ks 8..15: streamed T3 ----
        #pragma unroll
        for (int ks = 8; ks < 16; ++ks) {
            const int sc = ((ks * 4 + quad) ^ l7) * 8;
            short8 a  = *(const short8*)&rb[lcol * 512 + sc];
            short8 b2 = *(const short8*)&h2[sc];
            short8 b3 = sb0;
            sb0 = sb1;
            sb1 = *(const short8*)&hb3[(8 + ((ks - 6) & 7)) * 32 + quad * 8];
            acc[0] = MFMA(a, hfragA[0][ks], acc[0]);
            acc[1] = MFMA(a, hfragA[1][ks], acc[1]);
            acc[2] = MFMA(a, b2, acc[2]);
            acc[3] = MFMA(a, b3, acc[3]);
        }

        // ---- update u master + write new u into the OTHER buffer (swizzled) ----
        #pragma unroll
        for (int T = 0; T < 4; ++T) {
            #pragma unroll
            for (int r = 0; r < 4; ++r) {
                int m = quad * 4 + r;
                float g  = acc[T][r] + f_reg[T][r];
                float un = u_reg[T][r] - 0.01f * g;
                un = fminf(1.0f, fmaxf(-1.0f, un));
                u_reg[T][r] = un;
                int chunk = (w * 8 + T * 2 + (lcol >> 3)) ^ (m & 7);
                wb[m * 512 + chunk * 8 + l7] = f32_to_bf16(un);
            }
        }
        __syncthreads();   // wb writes visible; all rb reads complete
        u16t* t = rb; rb = wb; wb = t;
    }

    // ---- write final u (fp32) ----
    #pragma unroll
    for (int T = 0; T < 4; ++T) {
        int c = colbase + T * 16 + lcol;
        #pragma unroll
        for (int r = 0; r < 4; ++r)
            out[(long)(b0 + quad * 4 + r) * 512 + c] = u_reg[T][r];
    }
}

extern "C" void kernel_launch(void* const* d_in, const int* in_sizes, int n_in,
                              void* d_out, int out_size, void* d_ws, size_t ws_size,
                              hipStream_t stream) {
    // inputs: 0=x0 (unused), 1=xref, 2=H, 3=Phi, 4=Q
    const float* xref = (const float*)d_in[1];
    const float* H    = (const float*)d_in[2];
    const float* Phi  = (const float*)d_in[3];
    const float* Q    = (const float*)d_in[4];
    u16t* Hb = (u16t*)d_ws;                      // 512 KB

    (void)hipFuncSetAttribute((const void*)pgd_kernel7,
                              hipFuncAttributeMaxDynamicSharedMemorySize, DYN_LDS);

    convert_H_bf16<<<1024, 256, 0, stream>>>(H, Hb);
    pgd_kernel7<<<128, 512, DYN_LDS, stream>>>(xref, Hb, Phi, Q, (float*)d_out);
}

// Round 8
// 419.670 us; speedup vs baseline: 1.0631x; 1.0631x over previous
//
#include <hip/hip_runtime.h>

// LinearMPC PGD, round 8: round-5 skeleton (proven 214us), ONE change:
// T2's ks 8..15 reads moved from LDS to a second L2 rolling stream,
// equalizing the LDS pipe (192KB reads+writes ~3.1k cyc) and the L2 pipe
// (128KB stream ~3.1k cyc), which run concurrently.
// 128 blocks x 512 thr (8 waves, 2/SIMD). Wave w owns cols [w*64,+64) = 4 tiles:
//   T0,T1: bf16 B-frags in registers (128 regs)
//   T2:    ks 0..7 from LDS (133KB, iteration-invariant), ks 8..15 L2-streamed
//   T3:    ks 0..7 in registers (32 regs), ks 8..15 L2-streamed
// Lessons: R2 no cross-block comm; R3 spill sentinel = WRITE_SIZE; R5 LDS-pipe-bound;
// R6 never inline-asm MFMA; R7 don't restructure the skeleton (computed-XOR vaddrs
// + dbuf pointer swap doubled per-iter cost; keep immediate-offset ds_reads, 2 barriers).

typedef unsigned short u16t;
typedef __attribute__((ext_vector_type(8))) short short8;
typedef __attribute__((ext_vector_type(4))) float floatx4;

#define HLDS_BYTES (128 * 520 * 2)                 // 133,120
#define UBF_BYTES  (16 * 520 * 2)                  // 16,640
#define DYN_LDS    (HLDS_BYTES + UBF_BYTES)        // 149,760 < 160 KiB

__device__ __forceinline__ u16t f32_to_bf16(float x) {
    unsigned int u = __builtin_bit_cast(unsigned int, x);
    u = (u + 0x7FFFu + ((u >> 16) & 1u)) >> 16;   // RNE
    return (u16t)u;
}

__global__ void convert_H_bf16(const float* __restrict__ H, u16t* __restrict__ Hb) {
    int idx = blockIdx.x * 256 + threadIdx.x;   // 1024 x 256 = 262144
    Hb[idx] = f32_to_bf16(H[idx]);
}

#define MFMA(a, b, c) __builtin_amdgcn_mfma_f32_16x16x32_bf16((a), (b), (c), 0, 0, 0)

__global__ __launch_bounds__(512, 2)
void pgd_kernel8(const float* __restrict__ xref,   // [2048][65][8]
                 const float* __restrict__ H,      // [512][512] fp32
                 const u16t*  __restrict__ Hb,     // [512][512] bf16
                 const float* __restrict__ Phi,    // [65][8][8]
                 const float* __restrict__ Q,      // [8][8]
                 float* __restrict__ out)          // [2048][512]
{
    extern __shared__ __align__(16) char smem[];
    u16t* Hlds = (u16t*)smem;                               // [128][520]
    u16t (*u_bf)[520] = (u16t(*)[520])(smem + HLDS_BYTES);  // [16][520]

    const int tid  = threadIdx.x;
    const int lane = tid & 63;
    const int w    = tid >> 6;        // wave 0..7
    const int quad = lane >> 4;       // 0..3
    const int lcol = lane & 15;       // 0..15
    const int b0   = blockIdx.x * 16;
    const int colbase = w * 64;

    // ---- stage T2 H-rows into LDS: ldsrow r holds H[(r>>4)*64 + 32 + (r&15)] ----
    for (int e = tid; e < 8192; e += 512) {
        int r = e >> 6, c = e & 63;
        *(short8*)&Hlds[r * 520 + c * 8] =
            *(const short8*)&Hb[(long)((r >> 4) * 64 + 32 + (r & 15)) * 512 + c * 8];
    }
    // ---- zero u_bf ----
    {
        u16t* ub = &u_bf[0][0];
        for (int e = tid; e < 8320; e += 512) ub[e] = 0;
    }

    // ---- register B-fragments: T0,T1 full (128 regs) ----
    short8 hfragA[2][16];
    #pragma unroll
    for (int t = 0; t < 2; ++t) {
        const float* hrow = H + (long)(colbase + t * 16 + lcol) * 512;
        #pragma unroll
        for (int ks = 0; ks < 16; ++ks) {
            const float* hp = hrow + ks * 32 + quad * 8;
            short8 fr;
            #pragma unroll
            for (int j = 0; j < 8; ++j) fr[j] = (short)f32_to_bf16(hp[j]);
            hfragA[t][ks] = fr;
        }
    }
    // ---- register B-fragments: T3 ks 0..7 (32 regs) ----
    short8 frag3[8];
    {
        const float* hrow = H + (long)(colbase + 48 + lcol) * 512;
        #pragma unroll
        for (int ks = 0; ks < 8; ++ks) {
            const float* hp = hrow + ks * 32 + quad * 8;
            short8 fr;
            #pragma unroll
            for (int j = 0; j < 8; ++j) fr[j] = (short)f32_to_bf16(hp[j]);
            frag3[ks] = fr;
        }
    }

    // ---- f (linear term) + u master, per-thread regs, C/D layout ----
    float f_reg[4][4], u_reg[4][4];
    #pragma unroll
    for (int T = 0; T < 4; ++T) {
        int c = colbase + T * 16 + lcol;
        int k = c >> 3, i = c & 7;
        #pragma unroll
        for (int r = 0; r < 4; ++r) {
            int m = quad * 4 + r;
            const float* xr = xref + (long)(b0 + m) * 520;
            float s = 0.f;
            #pragma unroll
            for (int j = 0; j < 8; ++j) {
                float z = 0.f;
                #pragma unroll
                for (int l = 0; l < 8; ++l) z += Q[j * 8 + l] * (xr[k * 8 + l] - xr[l]);
                s += Phi[k * 64 + i * 8 + j] * z;
            }
            f_reg[T][r] = -2.0f * s;
            u_reg[T][r] = 0.0f;
        }
    }
    __syncthreads();

    // LDS b-read base for T2 ks 0..7 (LDS row = w*16 + lcol)
    const u16t* h2 = Hlds + (w * 16 + lcol) * 520;
    // L2 stream bases (iteration-invariant rows):
    //   T2 ks 8..15: H row colbase+32+lcol ; T3 ks 8..15: H row colbase+48+lcol
    const u16t* hb2 = Hb + (long)(colbase + 32 + lcol) * 512;
    const u16t* hb3 = Hb + (long)(colbase + 48 + lcol) * 512;

    // rolling +2 prefetch (wraps across iterations; addresses invariant)
    short8 p2a = *(const short8*)&hb2[8 * 32 + quad * 8];
    short8 p2b = *(const short8*)&hb2[9 * 32 + quad * 8];
    short8 p3a = *(const short8*)&hb3[8 * 32 + quad * 8];
    short8 p3b = *(const short8*)&hb3[9 * 32 + quad * 8];

    for (int it = 0; it < 100; ++it) {
        floatx4 acc[4];
        #pragma unroll
        for (int T = 0; T < 4; ++T) acc[T] = (floatx4){0.f, 0.f, 0.f, 0.f};

        // ---- ks 0..7: T2 from LDS, T3 from registers ----
        #pragma unroll
        for (int ks = 0; ks < 8; ++ks) {
            short8 a  = *(const short8*)&u_bf[lcol][ks * 32 + quad * 8];
            short8 b2 = *(const short8*)&h2[ks * 32 + quad * 8];
            acc[0] = MFMA(a, hfragA[0][ks], acc[0]);
            acc[1] = MFMA(a, hfragA[1][ks], acc[1]);
            acc[2] = MFMA(a, b2, acc[2]);
            acc[3] = MFMA(a, frag3[ks], acc[3]);
        }
        // ---- ks 8..15: T2 and T3 both L2-streamed (rolling +2) ----
        #pragma unroll
        for (int ks = 8; ks < 16; ++ks) {
            short8 a  = *(const short8*)&u_bf[lcol][ks * 32 + quad * 8];
            short8 b2 = p2a;
            p2a = p2b;
            p2b = *(const short8*)&hb2[(8 + ((ks - 6) & 7)) * 32 + quad * 8];
            short8 b3 = p3a;
            p3a = p3b;
            p3b = *(const short8*)&hb3[(8 + ((ks - 6) & 7)) * 32 + quad * 8];
            acc[0] = MFMA(a, hfragA[0][ks], acc[0]);
            acc[1] = MFMA(a, hfragA[1][ks], acc[1]);
            acc[2] = MFMA(a, b2, acc[2]);
            acc[3] = MFMA(a, b3, acc[3]);
        }

        // ---- update u master ----
        #pragma unroll
        for (int T = 0; T < 4; ++T)
            #pragma unroll
            for (int r = 0; r < 4; ++r) {
                float g  = acc[T][r] + f_reg[T][r];
                float un = u_reg[T][r] - 0.01f * g;
                un = fminf(1.0f, fmaxf(-1.0f, un));
                u_reg[T][r] = un;
            }

        __syncthreads();   // all waves done reading old u_bf
        #pragma unroll
        for (int T = 0; T < 4; ++T) {
            int c = colbase + T * 16 + lcol;
            #pragma unroll
            for (int r = 0; r < 4; ++r)
                u_bf[quad * 4 + r][c] = f32_to_bf16(u_reg[T][r]);
        }
        __syncthreads();   // new u_bf visible
    }

    // ---- write final u (fp32) ----
    #pragma unroll
    for (int T = 0; T < 4; ++T) {
        int c = colbase + T * 16 + lcol;
        #pragma unroll
        for (int r = 0; r < 4; ++r)
            out[(long)(b0 + quad * 4 + r) * 512 + c] = u_reg[T][r];
    }
}

extern "C" void kernel_launch(void* const* d_in, const int* in_sizes, int n_in,
                              void* d_out, int out_size, void* d_ws, size_t ws_size,
                              hipStream_t stream) {
    // inputs: 0=x0 (unused), 1=xref, 2=H, 3=Phi, 4=Q
    const float* xref = (const float*)d_in[1];
    const float* H    = (const float*)d_in[2];
    const float* Phi  = (const float*)d_in[3];
    const float* Q    = (const float*)d_in[4];
    u16t* Hb = (u16t*)d_ws;                      // 512 KB

    (void)hipFuncSetAttribute((const void*)pgd_kernel8,
                              hipFuncAttributeMaxDynamicSharedMemorySize, DYN_LDS);

    convert_H_bf16<<<1024, 256, 0, stream>>>(H, Hb);
    pgd_kernel8<<<128, 512, DYN_LDS, stream>>>(xref, H, Hb, Phi, Q, (float*)d_out);
}

// Round 9
// 331.778 us; speedup vs baseline: 1.3447x; 1.2649x over previous
//
#include <hip/hip_runtime.h>

// LinearMPC PGD, round 9: R4 skeleton (proven zero-spill 224us) + two surgical fixes:
//  (1) H is symmetric -> transposed MFMA roles (H=A-operand, u=B-operand).
//      All H/u LOADS byte-identical to before; C-layout transposes so each lane
//      holds 4 consecutive QP-cols of one batch row -> u_bf update = one b64
//      store per tile (was 16 scattered b16), final out = float4 stores.
//  (2) T3 L2 stream prefetch deepened 2 -> 8 (ring): consumer sits ~310 issue-cyc
//      behind its load > ~200cyc L2 latency (R8 lesson: 2-deep lockstep-stalls).
// Tiering (R4): T0,T1 reg-resident (128 regs), T2 LDS-resident (133KB), T3 fully
// L2-streamed (128KB/CU/iter). No frag3 -> ring regs are free, no spill.
// Lessons: R2 no cross-block comm; R3 spill sentinel=WRITE_SIZE; R6 no asm MFMA;
// R7 keep 2-barrier skeleton + immediate-offset ds_reads; R8 conflict counter =
// intrinsic 4cyc/b128 (not swizzle-fixable), shallow prefetch = lockstep stall.

typedef unsigned short u16t;
typedef __attribute__((ext_vector_type(8))) short short8;
typedef __attribute__((ext_vector_type(4))) short short4v;
typedef __attribute__((ext_vector_type(4))) float floatx4;

#define HLDS_BYTES (128 * 520 * 2)                 // 133,120
#define UBF_BYTES  (16 * 520 * 2)                  // 16,640
#define DYN_LDS    (HLDS_BYTES + UBF_BYTES)        // 149,760 < 160 KiB

__device__ __forceinline__ u16t f32_to_bf16(float x) {
    unsigned int u = __builtin_bit_cast(unsigned int, x);
    u = (u + 0x7FFFu + ((u >> 16) & 1u)) >> 16;   // RNE
    return (u16t)u;
}

__global__ void convert_H_bf16(const float* __restrict__ H, u16t* __restrict__ Hb) {
    int idx = blockIdx.x * 256 + threadIdx.x;   // 1024 x 256 = 262144
    Hb[idx] = f32_to_bf16(H[idx]);
}

#define MFMA(a, b, c) __builtin_amdgcn_mfma_f32_16x16x32_bf16((a), (b), (c), 0, 0, 0)

__global__ __launch_bounds__(512, 2)
void pgd_kernel9(const float* __restrict__ xref,   // [2048][65][8]
                 const u16t*  __restrict__ Hb,     // [512][512] bf16
                 const float* __restrict__ Phi,    // [65][8][8]
                 const float* __restrict__ Q,      // [8][8]
                 float* __restrict__ out)          // [2048][512]
{
    extern __shared__ __align__(16) char smem[];
    u16t* Hlds = (u16t*)smem;                               // [128][520]
    u16t (*u_bf)[520] = (u16t(*)[520])(smem + HLDS_BYTES);  // [16][520]

    const int tid  = threadIdx.x;
    const int lane = tid & 63;
    const int w    = tid >> 6;        // wave 0..7
    const int quad = lane >> 4;       // 0..3
    const int lcol = lane & 15;       // 0..15
    const int b0   = blockIdx.x * 16;
    const int colbase = w * 64;

    // ---- stage T2 H-rows into LDS: ldsrow r holds H[(r>>4)*64 + 32 + (r&15)] ----
    for (int e = tid; e < 8192; e += 512) {
        int r = e >> 6, c = e & 63;
        *(short8*)&Hlds[r * 520 + c * 8] =
            *(const short8*)&Hb[(long)((r >> 4) * 64 + 32 + (r & 15)) * 512 + c * 8];
    }
    // ---- zero u_bf ----
    {
        u16t* ub = &u_bf[0][0];
        for (int e = tid; e < 8320; e += 512) ub[e] = 0;
    }

    // ---- register A-fragments (H rows, byte-identical to old B-frags): T0,T1 ----
    short8 hfragA[2][16];
    #pragma unroll
    for (int t = 0; t < 2; ++t) {
        const u16t* hrow = Hb + (long)(colbase + t * 16 + lcol) * 512;
        #pragma unroll
        for (int ks = 0; ks < 16; ++ks)
            hfragA[t][ks] = *(const short8*)&hrow[ks * 32 + quad * 8];
    }

    // ---- f (linear term) + u master, TRANSPOSED C-layout:
    //      lane (quad,lcol): batch row = b0+lcol, QP col = colbase+T*16+quad*4+r ----
    float f_reg[4][4], u_reg[4][4];
    {
        const float* xr = xref + (long)(b0 + lcol) * 520;
        #pragma unroll
        for (int T = 0; T < 4; ++T) {
            #pragma unroll
            for (int r = 0; r < 4; ++r) {
                int c = colbase + T * 16 + quad * 4 + r;
                int k = c >> 3, i = c & 7;
                float s = 0.f;
                #pragma unroll
                for (int j = 0; j < 8; ++j) {
                    float z = 0.f;
                    #pragma unroll
                    for (int l = 0; l < 8; ++l) z += Q[j * 8 + l] * (xr[k * 8 + l] - xr[l]);
                    s += Phi[k * 64 + i * 8 + j] * z;
                }
                f_reg[T][r] = -2.0f * s;
                u_reg[T][r] = 0.0f;
            }
        }
    }
    __syncthreads();

    // LDS A-read base for T2 (H row colbase+32+lcol lives at LDS row w*16+lcol)
    const u16t* h2 = Hlds + (w * 16 + lcol) * 520;
    // T3 fully L2-streamed: H row colbase+48+lcol, 8-deep rolling ring
    const u16t* hb3 = Hb + (long)(colbase + 48 + lcol) * 512;
    short8 ring[8];
    #pragma unroll
    for (int i = 0; i < 8; ++i)
        ring[i] = *(const short8*)&hb3[i * 32 + quad * 8];

    for (int it = 0; it < 100; ++it) {
        floatx4 acc[4];
        #pragma unroll
        for (int T = 0; T < 4; ++T) acc[T] = (floatx4){0.f, 0.f, 0.f, 0.f};

        #pragma unroll
        for (int ks = 0; ks < 16; ++ks) {
            short8 a  = *(const short8*)&u_bf[lcol][ks * 32 + quad * 8];  // u as B-frag
            short8 b2 = *(const short8*)&h2[ks * 32 + quad * 8];
            short8 b3 = ring[ks & 7];
            ring[ks & 7] = *(const short8*)&hb3[((ks + 8) & 15) * 32 + quad * 8];
            acc[0] = MFMA(hfragA[0][ks], a, acc[0]);
            acc[1] = MFMA(hfragA[1][ks], a, acc[1]);
            acc[2] = MFMA(b2, a, acc[2]);
            acc[3] = MFMA(b3, a, acc[3]);
        }

        // ---- update u master (registers only) ----
        #pragma unroll
        for (int T = 0; T < 4; ++T)
            #pragma unroll
            for (int r = 0; r < 4; ++r) {
                float g  = acc[T][r] + f_reg[T][r];
                float un = u_reg[T][r] - 0.01f * g;
                un = fminf(1.0f, fmaxf(-1.0f, un));
                u_reg[T][r] = un;
            }

        __syncthreads();   // all waves done reading old u_bf
        // ---- write new u: 4 consecutive cols per tile -> one b64 store each ----
        #pragma unroll
        for (int T = 0; T < 4; ++T) {
            short4v nv;
            #pragma unroll
            for (int r = 0; r < 4; ++r) nv[r] = (short)f32_to_bf16(u_reg[T][r]);
            *(short4v*)&u_bf[lcol][colbase + T * 16 + quad * 4] = nv;
        }
        __syncthreads();   // new u_bf visible
    }

    // ---- write final u (fp32), float4 per tile ----
    #pragma unroll
    for (int T = 0; T < 4; ++T) {
        floatx4 v;
        #pragma unroll
        for (int r = 0; r < 4; ++r) v[r] = u_reg[T][r];
        *(floatx4*)&out[(long)(b0 + lcol) * 512 + colbase + T * 16 + quad * 4] = v;
    }
}

extern "C" void kernel_launch(void* const* d_in, const int* in_sizes, int n_in,
                              void* d_out, int out_size, void* d_ws, size_t ws_size,
                              hipStream_t stream) {
    // inputs: 0=x0 (unused), 1=xref, 2=H, 3=Phi, 4=Q
    const float* xref = (const float*)d_in[1];
    const float* H    = (const float*)d_in[2];
    const float* Phi  = (const float*)d_in[3];
    const float* Q    = (const float*)d_in[4];
    u16t* Hb = (u16t*)d_ws;                      // 512 KB

    (void)hipFuncSetAttribute((const void*)pgd_kernel9,
                              hipFuncAttributeMaxDynamicSharedMemorySize, DYN_LDS);

    convert_H_bf16<<<1024, 256, 0, stream>>>(H, Hb);
    pgd_kernel9<<<128, 512, DYN_LDS, stream>>>(xref, Hb, Phi, Q, (float*)d_out);
}

// Round 10
// 264.054 us; speedup vs baseline: 1.6896x; 1.2565x over previous
//
#include <hip/hip_runtime.h>

// LinearMPC PGD, round 10: R5 skeleton VERBATIM (proven 214us best), one change:
// LDS layouts switched from row-major(+pad) to FRAGMENT-ORDER slabs.
//   uA[ks][lane][8]  : wave reads 1024 contiguous B per ks -> conflict-free,
//   H2s[w][ks][lane][8]: same for the T2 H tile.
// Theorem (R5/R7 counters): any 16B-aligned row stride lands all 64 lanes in
// <=8 banks (stride=0 mod 4 banks) -> 8-way conflicts unfixable by pad/XOR;
// fragment-order is the only conflict-free b128 layout. ks offsets stay
// compile-time immediates (preserves R5's loop scheduling exactly).
// Tiering per wave (cols [w*64,+64)): T0,T1 reg frags (128), T2 LDS slab,
// T3 = frag3 ks0-7 (32 regs) + 2-deep rolling L2 stream ks8-15.
// Lessons: R2 no cross-block comm; R3 spill sentinel=WRITE_SIZE; R6 no asm MFMA;
// R7/R8/R9 never restructure the ks-loop/skeleton; R10: only addresses changed.

typedef unsigned short u16t;
typedef __attribute__((ext_vector_type(8))) short short8;
typedef __attribute__((ext_vector_type(4))) float floatx4;

#define UA_SHORTS   (16 * 512)                 // 16 KB  : u fragment slabs
#define H2_SHORTS   (8 * 16 * 512)             // 128 KB : T2 H fragment slabs
#define DYN_LDS     ((UA_SHORTS + H2_SHORTS) * 2)   // 147,456 B < 160 KiB

__device__ __forceinline__ u16t f32_to_bf16(float x) {
    unsigned int u = __builtin_bit_cast(unsigned int, x);
    u = (u + 0x7FFFu + ((u >> 16) & 1u)) >> 16;   // RNE
    return (u16t)u;
}

__global__ void convert_H_bf16(const float* __restrict__ H, u16t* __restrict__ Hb) {
    int idx = blockIdx.x * 256 + threadIdx.x;   // 1024 x 256 = 262144
    Hb[idx] = f32_to_bf16(H[idx]);
}

#define MFMA(a, b, c) __builtin_amdgcn_mfma_f32_16x16x32_bf16((a), (b), (c), 0, 0, 0)

__global__ __launch_bounds__(512, 2)
void pgd_kernel10(const float* __restrict__ xref,   // [2048][65][8]
                  const float* __restrict__ H,      // [512][512] fp32
                  const u16t*  __restrict__ Hb,     // [512][512] bf16
                  const float* __restrict__ Phi,    // [65][8][8]
                  const float* __restrict__ Q,      // [8][8]
                  float* __restrict__ out)          // [2048][512]
{
    extern __shared__ __align__(16) char smem[];
    u16t* uA  = (u16t*)smem;                        // [16 ks][64 lane][8]
    u16t* H2s = (u16t*)(smem + UA_SHORTS * 2);      // [8 w][16 ks][64 lane][8]

    const int tid  = threadIdx.x;
    const int lane = tid & 63;
    const int w    = tid >> 6;        // wave 0..7
    const int quad = lane >> 4;       // 0..3
    const int lcol = lane & 15;       // 0..15
    const int b0   = blockIdx.x * 16;
    const int colbase = w * 64;

    // ---- stage T2 H rows into fragment-order slabs ----
    // chunk e: w'=e>>10, ks=(e>>6)&15, lane'=e&63 (quad'=lane'>>4, lcol'=lane'&15)
    // holds H[w'*64+32+lcol'][ks*32+quad'*8 .. +7]
    for (int e = tid; e < 8192; e += 512) {
        int wp = e >> 10, ks = (e >> 6) & 15, lp = e & 63;
        int qp = lp >> 4, cp = lp & 15;
        *(short8*)&H2s[e * 8] =
            *(const short8*)&Hb[(long)(wp * 64 + 32 + cp) * 512 + ks * 32 + qp * 8];
    }
    // ---- zero uA (u0 = 0) ----
    for (int e = tid; e < UA_SHORTS / 2; e += 512) ((unsigned*)uA)[e] = 0u;

    // ---- register B-fragments: T0,T1 full (128 regs) ----
    short8 hfragA[2][16];
    #pragma unroll
    for (int t = 0; t < 2; ++t) {
        const float* hrow = H + (long)(colbase + t * 16 + lcol) * 512;
        #pragma unroll
        for (int ks = 0; ks < 16; ++ks) {
            const float* hp = hrow + ks * 32 + quad * 8;
            short8 fr;
            #pragma unroll
            for (int j = 0; j < 8; ++j) fr[j] = (short)f32_to_bf16(hp[j]);
            hfragA[t][ks] = fr;
        }
    }
    // ---- register B-fragments: T3 ks 0..7 (32 regs) ----
    short8 frag3[8];
    {
        const float* hrow = H + (long)(colbase + 48 + lcol) * 512;
        #pragma unroll
        for (int ks = 0; ks < 8; ++ks) {
            const float* hp = hrow + ks * 32 + quad * 8;
            short8 fr;
            #pragma unroll
            for (int j = 0; j < 8; ++j) fr[j] = (short)f32_to_bf16(hp[j]);
            frag3[ks] = fr;
        }
    }

    // ---- f (linear term) + u master, per-thread regs, C/D layout ----
    float f_reg[4][4], u_reg[4][4];
    #pragma unroll
    for (int T = 0; T < 4; ++T) {
        int c = colbase + T * 16 + lcol;
        int k = c >> 3, i = c & 7;
        #pragma unroll
        for (int r = 0; r < 4; ++r) {
            int m = quad * 4 + r;
            const float* xr = xref + (long)(b0 + m) * 520;
            float s = 0.f;
            #pragma unroll
            for (int j = 0; j < 8; ++j) {
                float z = 0.f;
                #pragma unroll
                for (int l = 0; l < 8; ++l) z += Q[j * 8 + l] * (xr[k * 8 + l] - xr[l]);
                s += Phi[k * 64 + i * 8 + j] * z;
            }
            f_reg[T][r] = -2.0f * s;
            u_reg[T][r] = 0.0f;
        }
    }
    __syncthreads();

    // fragment-order read bases (lane-dependent part folded once; ks*512 immediate)
    const u16t* uA_l  = uA  + lane * 8;
    const u16t* h2_l  = H2s + (w * 16 * 512) + lane * 8;
    // L2 stream: T3 ks 8..15 of H row colbase+48+lcol, rolling +2 (R5-verbatim)
    const u16t* hb3 = Hb + (long)(colbase + 48 + lcol) * 512;
    short8 sb0 = *(const short8*)&hb3[8 * 32 + quad * 8];
    short8 sb1 = *(const short8*)&hb3[9 * 32 + quad * 8];

    // u-write address components (fragment-order scatter), per-thread constants
    // value (T,r): ks=w*2+(T>>1); lane_a=quad_a*16+quad*4+r, quad_a=(T*2+(lcol>>3))&3
    const int j7 = lcol & 7;

    for (int it = 0; it < 100; ++it) {
        floatx4 acc[4];
        #pragma unroll
        for (int T = 0; T < 4; ++T) acc[T] = (floatx4){0.f, 0.f, 0.f, 0.f};

        // ---- ks 0..7: T2 from LDS slab, T3 from registers ----
        #pragma unroll
        for (int ks = 0; ks < 8; ++ks) {
            short8 a  = *(const short8*)&uA_l[ks * 512];
            short8 b2 = *(const short8*)&h2_l[ks * 512];
            acc[0] = MFMA(a, hfragA[0][ks], acc[0]);
            acc[1] = MFMA(a, hfragA[1][ks], acc[1]);
            acc[2] = MFMA(a, b2, acc[2]);
            acc[3] = MFMA(a, frag3[ks], acc[3]);
        }
        // ---- ks 8..15: T2 from LDS slab, T3 L2-streamed (rolling +2) ----
        #pragma unroll
        for (int ks = 8; ks < 16; ++ks) {
            short8 a  = *(const short8*)&uA_l[ks * 512];
            short8 b2 = *(const short8*)&h2_l[ks * 512];
            short8 b3 = sb0;
            sb0 = sb1;
            sb1 = *(const short8*)&hb3[(8 + ((ks - 6) & 7)) * 32 + quad * 8];
            acc[0] = MFMA(a, hfragA[0][ks], acc[0]);
            acc[1] = MFMA(a, hfragA[1][ks], acc[1]);
            acc[2] = MFMA(a, b2, acc[2]);
            acc[3] = MFMA(a, b3, acc[3]);
        }

        // ---- update u master ----
        #pragma unroll
        for (int T = 0; T < 4; ++T)
            #pragma unroll
            for (int r = 0; r < 4; ++r) {
                float g  = acc[T][r] + f_reg[T][r];
                float un = u_reg[T][r] - 0.01f * g;
                un = fminf(1.0f, fmaxf(-1.0f, un));
                u_reg[T][r] = un;
            }

        __syncthreads();   // all waves done reading old uA
        // ---- scatter new u into fragment-order slabs (b16 stores, as R5) ----
        #pragma unroll
        for (int T = 0; T < 4; ++T) {
            int ks_a   = w * 2 + (T >> 1);
            int quad_a = (T * 2 + (lcol >> 3)) & 3;
            #pragma unroll
            for (int r = 0; r < 4; ++r) {
                int lane_a = quad_a * 16 + quad * 4 + r;
                uA[ks_a * 512 + lane_a * 8 + j7] = f32_to_bf16(u_reg[T][r]);
            }
        }
        __syncthreads();   // new uA visible
    }

    // ---- write final u (fp32) ----
    #pragma unroll
    for (int T = 0; T < 4; ++T) {
        int c = colbase + T * 16 + lcol;
        #pragma unroll
        for (int r = 0; r < 4; ++r)
            out[(long)(b0 + quad * 4 + r) * 512 + c] = u_reg[T][r];
    }
}

extern "C" void kernel_launch(void* const* d_in, const int* in_sizes, int n_in,
                              void* d_out, int out_size, void* d_ws, size_t ws_size,
                              hipStream_t stream) {
    // inputs: 0=x0 (unused), 1=xref, 2=H, 3=Phi, 4=Q
    const float* xref = (const float*)d_in[1];
    const float* H    = (const float*)d_in[2];
    const float* Phi  = (const float*)d_in[3];
    const float* Q    = (const float*)d_in[4];
    u16t* Hb = (u16t*)d_ws;                      // 512 KB

    (void)hipFuncSetAttribute((const void*)pgd_kernel10,
                              hipFuncAttributeMaxDynamicSharedMemorySize, DYN_LDS);

    convert_H_bf16<<<1024, 256, 0, stream>>>(H, Hb);
    pgd_kernel10<<<128, 512, DYN_LDS, stream>>>(xref, H, Hb, Phi, Q, (float*)d_out);
}